// Round 4
// baseline (9480.895 us; speedup 1.0000x reference)
//
#include <hip/hip_runtime.h>
#include <hip/hip_bf16.h>
#include <math.h>

// Problem constants (E83CircularTowerCell): T=2048, B=16, D=1024, n=64, K=3
#define TT 2048
#define BB_ 16
#define DD 1024
#define NN 64
#define KK 3
#define PP 448   // K*2*n + n = 384 + 64

__device__ __forceinline__ float sigmoidf_(float x) {
    return 1.0f / (1.0f + __expf(-x));
}

// LDS-ordering-only barrier: leaves global (vmcnt) loads in flight.
#define LDS_BARRIER() __asm__ volatile("s_waitcnt lgkmcnt(0)\n\ts_barrier" ::: "memory")

__device__ __forceinline__ void load4(float d[4], const float* p) {
    float4 t = *(const float4*)p;
    d[0] = t.x; d[1] = t.y; d[2] = t.z; d[3] = t.w;
}

// Selective butterfly: 4 partial components per lane, reduced across the
// 4-lane xor-group {mb, 2mb}; lane ends with full sum of component s.
__device__ __forceinline__ float sel_reduce4(const float v[4], int s, int mb) {
    const int s0 = s & 1, s1 = (s >> 1) & 1;
    float k0 = s0 ? v[1] : v[0], d0 = s0 ? v[0] : v[1];
    float k1 = s0 ? v[3] : v[2], d1 = s0 ? v[2] : v[3];
    float a0 = k0 + __shfl_xor(d0, mb, 64);
    float a1 = k1 + __shfl_xor(d1, mb, 64);
    float kb = s1 ? a1 : a0, db = s1 ? a0 : a1;
    return kb + __shfl_xor(db, 2 * mb, 64);
}

// ---------------------------------------------------------------------------
// GEMM: kvq[(t*B+b)][p] = sum_d x[t,b,d] * Wcat[p][d]; k-tiles (p0=0,128,256)
// are L2-normalized in the epilogue.
// ---------------------------------------------------------------------------
__global__ __launch_bounds__(256) void proj_gemm_kernel(
    const float* __restrict__ x,
    const float* __restrict__ Wkv,
    const float* __restrict__ Wq,
    float* __restrict__ kvq)
{
    __shared__ float As[16][68];
    __shared__ float Bs[16][68];

    const int tid = threadIdx.x;
    const int m0 = blockIdx.x * 64;
    const int p0 = blockIdx.y * 64;
    const int tx = tid & 15;
    const int ty = tid >> 4;
    const int lrow = tid >> 2;
    const int lk   = (tid & 3) * 4;

    const int p = p0 + lrow;
    const float* wrow = (p < 384) ? (Wkv + (size_t)p * DD)
                                  : (Wq  + (size_t)(p - 384) * DD);
    const float* arow = x + (size_t)(m0 + lrow) * DD;

    float acc[4][4] = {};

    for (int kb = 0; kb < DD; kb += 16) {
        const float4 a4 = *(const float4*)(arow + kb + lk);
        const float4 b4 = *(const float4*)(wrow + kb + lk);
        __syncthreads();
        As[lk + 0][lrow] = a4.x; As[lk + 1][lrow] = a4.y;
        As[lk + 2][lrow] = a4.z; As[lk + 3][lrow] = a4.w;
        Bs[lk + 0][lrow] = b4.x; Bs[lk + 1][lrow] = b4.y;
        Bs[lk + 2][lrow] = b4.z; Bs[lk + 3][lrow] = b4.w;
        __syncthreads();
        #pragma unroll
        for (int kk = 0; kk < 16; ++kk) {
            const float4 av = *(const float4*)&As[kk][ty * 4];
            const float4 bv = *(const float4*)&Bs[kk][tx * 4];
            const float a[4] = {av.x, av.y, av.z, av.w};
            const float b[4] = {bv.x, bv.y, bv.z, bv.w};
            #pragma unroll
            for (int ia = 0; ia < 4; ++ia)
                #pragma unroll
                for (int ib = 0; ib < 4; ++ib)
                    acc[ia][ib] += a[ia] * b[ib];
        }
    }

    if (p0 == 0 || p0 == 128 || p0 == 256) {
        #pragma unroll
        for (int ia = 0; ia < 4; ++ia) {
            float ss = acc[ia][0] * acc[ia][0] + acc[ia][1] * acc[ia][1]
                     + acc[ia][2] * acc[ia][2] + acc[ia][3] * acc[ia][3];
            #pragma unroll
            for (int m = 1; m <= 8; m <<= 1) ss += __shfl_xor(ss, m, 64);
            const float sc = 1.0f / (sqrtf(ss) + 1e-6f);
            #pragma unroll
            for (int ib = 0; ib < 4; ++ib) acc[ia][ib] *= sc;
        }
    }

    #pragma unroll
    for (int ia = 0; ia < 4; ++ia) {
        float4 v = make_float4(acc[ia][0], acc[ia][1], acc[ia][2], acc[ia][3]);
        *(float4*)&kvq[(size_t)(m0 + ty * 4 + ia) * PP + p0 + tx * 4] = v;
    }
}

// ---------------------------------------------------------------------------
// Distributed ring scan: 48 cooperative blocks, one per (b,k). 256 threads
// (4 waves, 1 wave/SIMD), wave q owns rows 16q..16q+15 of M[k]; lane (tr,tc)
// owns the 4x4 tile at (16q+4tr, 4tc). Cross-block gate exchange via
// agent-scope atomics with mod-3 slot buffering (ring back-pressure gives
// exactly 3 steps of overwrite distance). Flag equality-poll (value t+1) is
// immune to 0xAA workspace poison; 65k-spin bailout prevents hangs.
// ---------------------------------------------------------------------------
__global__ __launch_bounds__(256) void scan_ring_kernel(
    const float* __restrict__ kvq,
    const float* __restrict__ M_init,
    const float* __restrict__ B_gates,
    float* __restrict__ d_out,
    float* __restrict__ gbuf,     // [B][K][3][128]  rg|cg per slot
    int* __restrict__ flags)      // [B][K][3]
{
    // XCD co-location: blocks of one batch's ring land on the same XCD.
    const int g    = blockIdx.x;
    const int xcd  = g & 7;
    const int slot = g >> 3;            // 0..5
    const int b    = xcd + 8 * (slot / 3);
    const int k    = slot - 3 * (slot / 3);
    const int kp   = (k + 2) % 3;       // gate target (k-1 mod 3)

    const int tid  = threadIdx.x;
    const int q    = tid >> 6;
    const int lane = tid & 63;
    const int tr   = lane >> 4;
    const int tc   = lane & 15;
    const int row0 = 16 * q + 4 * tr;
    const int col0 = 4 * tc;
    const int s3   = tc & 3;            // component this lane finalizes
    const int rowS = row0 + s3;

    __shared__ float rs_lds[2][64];
    __shared__ float cs_lds[2][4][64];
    __shared__ float dl_lds[2][64];

    float M[4][4];
    #pragma unroll
    for (int i = 0; i < 4; ++i)
        load4(M[i], M_init + (((size_t)k * BB_ + b) * NN + row0 + i) * NN + col0);

    // Publisher bias (wave 0): B_gates[kp][i] is used for BOTH row i and col i.
    const float pub_bias = B_gates[kp * NN + lane];

    float* outp = d_out;                           // [T][B][n]
    float* Mout = d_out + (size_t)TT * BB_ * NN;   // [K][B][n][n]

    float* pg  = gbuf  + ((size_t)(b * 3 + kp) * 3) * 128;  // gates I produce
    float* myg = gbuf  + ((size_t)(b * 3 + k)  * 3) * 128;  // gates I consume
    int*   pf  = flags + (b * 3 + kp) * 3;
    int*   mf  = flags + (b * 3 + k) * 3;

    // Per-lane load offsets within a (t,b) row of kvq.
    const int o_knc = k * 128 + col0;
    const int o_wpc = kp * 128 + col0;
    const int o_wpr = kp * 128 + row0;
    const int o_v   = k * 128 + 64 + rowS;
    const int o_q   = 384 + col0;

    const float* kvt = kvq + (size_t)b * PP;   // row (t=0, b); +BB_*PP per step
    float knc[4], wpc[4], wpr[4], qc[4], vs;
    load4(knc, kvt + o_knc);
    load4(wpc, kvt + o_wpc);
    load4(wpr, kvt + o_wpr);
    vs = kvt[o_v];
    if (k == 0) load4(qc, kvt + o_q);

    for (int t = 0; t < TT; ++t) {
        const int pb = t & 1;
        const int sl = t - (t / 3) * 3;     // t % 3

        // Prefetch t+1 (stays in flight across the lgkm-only barrier).
        const float* kvn = (t + 1 < TT) ? (kvt + (size_t)BB_ * PP) : kvt;
        float nk[4], nwc[4], nwr[4], nq[4], nvs;
        load4(nk,  kvn + o_knc);
        load4(nwc, kvn + o_wpc);
        load4(nwr, kvn + o_wpr);
        nvs = kvn[o_v];
        if (k == 0) load4(nq, kvn + o_q);

        // Fused 3-matvec partials over the lane's 4x4 tile.
        float rp[4] = {}, sp[4] = {}, cp[4] = {};
        #pragma unroll
        for (int i = 0; i < 4; ++i) {
            #pragma unroll
            for (int j = 0; j < 4; ++j) {
                const float m_ = M[i][j];
                rp[i] += m_ * knc[j];   // M[k]   @ kn[k]    (retrieve)
                sp[i] += m_ * wpc[j];   // M[k]   @ kn[kp]   (row gate of kp)
                cp[j] += m_ * wpr[i];   // M[k]^T @ kn[kp]   (col gate of kp)
            }
        }

        // Row-direction reduces (in-wave, 16 tc-lanes).
        float rsv = sel_reduce4(sp, s3, 1);
        rsv += __shfl_xor(rsv, 4, 64);
        rsv += __shfl_xor(rsv, 8, 64);
        float rtv = sel_reduce4(rp, s3, 1);
        rtv += __shfl_xor(rtv, 4, 64);
        rtv += __shfl_xor(rtv, 8, 64);
        const float dv = vs - rtv;              // delta for row rowS
        // Col-direction partial (in-wave, 4 tr-lanes; 16 rows of this wave).
        const float csv = sel_reduce4(cp, tr, 16);

        if (tc < 4) {
            rs_lds[pb][row0 + tc] = rsv;
            dl_lds[pb][row0 + tc] = dv;
        }
        cs_lds[pb][q][col0 + tr] = csv;
        LDS_BARRIER();

        // Wave 0 publishes neighbor's gates (cache-bypass agent atomics).
        if (tid < 64) {
            const float rg_ = sigmoidf_(rs_lds[pb][tid] + pub_bias);
            const float cg_ = sigmoidf_(cs_lds[pb][0][tid] + cs_lds[pb][1][tid] +
                                        cs_lds[pb][2][tid] + cs_lds[pb][3][tid] + pub_bias);
            float* dst = pg + sl * 128;
            __hip_atomic_store(dst + tid,      rg_, __ATOMIC_RELAXED, __HIP_MEMORY_SCOPE_AGENT);
            __hip_atomic_store(dst + 64 + tid, cg_, __ATOMIC_RELAXED, __HIP_MEMORY_SCOPE_AGENT);
            if (tid == 0)
                __hip_atomic_store(pf + sl, t + 1, __ATOMIC_RELEASE, __HIP_MEMORY_SCOPE_AGENT);
        }

        // Poll my gates (equality: poisoned 0xAA never matches t+1).
        {
            const int want = t + 1;
            int* fp = mf + sl;
            int spins = 0;
            while (__hip_atomic_load(fp, __ATOMIC_ACQUIRE, __HIP_MEMORY_SCOPE_AGENT) != want) {
                __builtin_amdgcn_s_sleep(1);
                if (++spins > 65536) break;   // bail: fail bench, don't hang it
            }
        }
        const float* src = myg + sl * 128;
        float rg[4], cg[4];
        #pragma unroll
        for (int i = 0; i < 4; ++i)
            rg[i] = __hip_atomic_load(src + row0 + i, __ATOMIC_RELAXED, __HIP_MEMORY_SCOPE_AGENT);
        #pragma unroll
        for (int j = 0; j < 4; ++j)
            cg[j] = __hip_atomic_load(src + 64 + col0 + j, __ATOMIC_RELAXED, __HIP_MEMORY_SCOPE_AGENT);

        // Delta for my 4 rows (broadcast read).
        const float4 d4 = *(const float4*)&dl_lds[pb][row0];
        const float dd[4] = {d4.x, d4.y, d4.z, d4.w};

        // Update: M = rg_i * (M * cg_j) + delta_i * kn_j
        #pragma unroll
        for (int i = 0; i < 4; ++i) {
            #pragma unroll
            for (int j = 0; j < 4; ++j)
                M[i][j] = rg[i] * (M[i][j] * cg[j]) + dd[i] * knc[j];
        }

        // Output (k==0): Sq = M_new @ q_t, SiLU.
        if (k == 0) {
            float op[4] = {};
            #pragma unroll
            for (int i = 0; i < 4; ++i)
                #pragma unroll
                for (int j = 0; j < 4; ++j) op[i] += M[i][j] * qc[j];
            float ov = sel_reduce4(op, s3, 1);
            ov += __shfl_xor(ov, 4, 64);
            ov += __shfl_xor(ov, 8, 64);
            if (tc < 4)
                outp[((size_t)t * BB_ + b) * NN + rowS] = ov * sigmoidf_(ov);
        }

        // Rotate prefetch.
        #pragma unroll
        for (int j = 0; j < 4; ++j) {
            knc[j] = nk[j]; wpc[j] = nwc[j]; wpr[j] = nwr[j]; qc[j] = nq[j];
        }
        vs  = nvs;
        kvt = kvn;
    }

    // Final state write-out.
    #pragma unroll
    for (int i = 0; i < 4; ++i) {
        float4 v = make_float4(M[i][0], M[i][1], M[i][2], M[i][3]);
        *(float4*)&Mout[(((size_t)k * BB_ + b) * NN + row0 + i) * NN + col0] = v;
    }
}

extern "C" void kernel_launch(void* const* d_in, const int* in_sizes, int n_in,
                              void* d_out, int out_size, void* d_ws, size_t ws_size,
                              hipStream_t stream) {
    const float* x       = (const float*)d_in[0];
    const float* M_init  = (const float*)d_in[1];
    const float* W_kv    = (const float*)d_in[2];
    const float* W_q     = (const float*)d_in[3];
    const float* B_gates = (const float*)d_in[4];
    float* out = (float*)d_out;

    float* kvq = (float*)d_ws;                              // 58,720,256 B
    const size_t kvq_bytes = (size_t)TT * BB_ * PP * 4;
    float* gbuf = (float*)((char*)d_ws + kvq_bytes);        // 73,728 B
    int* flags  = (int*)((char*)d_ws + kvq_bytes + (size_t)BB_ * KK * 3 * 128 * 4);

    dim3 ggrid(TT * BB_ / 64, PP / 64);
    proj_gemm_kernel<<<ggrid, 256, 0, stream>>>(x, W_kv, W_q, kvq);

    const float* kvq_c = kvq;
    void* args[] = { (void*)&kvq_c, (void*)&M_init, (void*)&B_gates,
                     (void*)&out, (void*)&gbuf, (void*)&flags };
    hipLaunchCooperativeKernel((const void*)scan_ring_kernel,
                               dim3(BB_ * KK), dim3(256), args, 0, stream);
}

// Round 5
// 2883.276 us; speedup vs baseline: 3.2882x; 3.2882x over previous
//
#include <hip/hip_runtime.h>
#include <hip/hip_bf16.h>
#include <math.h>

// Problem constants (E83CircularTowerCell): T=2048, B=16, D=1024, n=64, K=3
#define TT 2048
#define BB_ 16
#define DD 1024
#define NN 64
#define KK 3
#define PP 448   // K*2*n + n = 384 + 64

__device__ __forceinline__ float sigmoidf_(float x) {
    return 1.0f / (1.0f + __expf(-x));
}

// LDS-ordering-only barrier: leaves global (vmcnt) loads in flight.
#define LDS_BARRIER() __asm__ volatile("s_waitcnt lgkmcnt(0)\n\ts_barrier" ::: "memory")

__device__ __forceinline__ void load4(float d[4], const float* p) {
    float4 t = *(const float4*)p;
    d[0] = t.x; d[1] = t.y; d[2] = t.z; d[3] = t.w;
}

// Selective butterfly: 4 partial components per lane, reduced across the
// 4-lane xor-group {mb, 2mb}; lane ends with full sum of component s.
__device__ __forceinline__ float sel_reduce4(const float v[4], int s, int mb) {
    const int s0 = s & 1, s1 = (s >> 1) & 1;
    float k0 = s0 ? v[1] : v[0], d0 = s0 ? v[0] : v[1];
    float k1 = s0 ? v[3] : v[2], d1 = s0 ? v[2] : v[3];
    float a0 = k0 + __shfl_xor(d0, mb, 64);
    float a1 = k1 + __shfl_xor(d1, mb, 64);
    float kb = s1 ? a1 : a0, db = s1 ? a0 : a1;
    return kb + __shfl_xor(db, 2 * mb, 64);
}

// ---------------------------------------------------------------------------
// GEMM: kvq[(t*B+b)][p] = sum_d x[t,b,d] * Wcat[p][d]; k-tiles (p0=0,128,256)
// are L2-normalized in the epilogue.
// ---------------------------------------------------------------------------
__global__ __launch_bounds__(256) void proj_gemm_kernel(
    const float* __restrict__ x,
    const float* __restrict__ Wkv,
    const float* __restrict__ Wq,
    float* __restrict__ kvq)
{
    __shared__ float As[16][68];
    __shared__ float Bs[16][68];

    const int tid = threadIdx.x;
    const int m0 = blockIdx.x * 64;
    const int p0 = blockIdx.y * 64;
    const int tx = tid & 15;
    const int ty = tid >> 4;
    const int lrow = tid >> 2;
    const int lk   = (tid & 3) * 4;

    const int p = p0 + lrow;
    const float* wrow = (p < 384) ? (Wkv + (size_t)p * DD)
                                  : (Wq  + (size_t)(p - 384) * DD);
    const float* arow = x + (size_t)(m0 + lrow) * DD;

    float acc[4][4] = {};

    for (int kb = 0; kb < DD; kb += 16) {
        const float4 a4 = *(const float4*)(arow + kb + lk);
        const float4 b4 = *(const float4*)(wrow + kb + lk);
        __syncthreads();
        As[lk + 0][lrow] = a4.x; As[lk + 1][lrow] = a4.y;
        As[lk + 2][lrow] = a4.z; As[lk + 3][lrow] = a4.w;
        Bs[lk + 0][lrow] = b4.x; Bs[lk + 1][lrow] = b4.y;
        Bs[lk + 2][lrow] = b4.z; Bs[lk + 3][lrow] = b4.w;
        __syncthreads();
        #pragma unroll
        for (int kk = 0; kk < 16; ++kk) {
            const float4 av = *(const float4*)&As[kk][ty * 4];
            const float4 bv = *(const float4*)&Bs[kk][tx * 4];
            const float a[4] = {av.x, av.y, av.z, av.w};
            const float b[4] = {bv.x, bv.y, bv.z, bv.w};
            #pragma unroll
            for (int ia = 0; ia < 4; ++ia)
                #pragma unroll
                for (int ib = 0; ib < 4; ++ib)
                    acc[ia][ib] += a[ia] * b[ib];
        }
    }

    if (p0 == 0 || p0 == 128 || p0 == 256) {
        #pragma unroll
        for (int ia = 0; ia < 4; ++ia) {
            float ss = acc[ia][0] * acc[ia][0] + acc[ia][1] * acc[ia][1]
                     + acc[ia][2] * acc[ia][2] + acc[ia][3] * acc[ia][3];
            #pragma unroll
            for (int m = 1; m <= 8; m <<= 1) ss += __shfl_xor(ss, m, 64);
            const float sc = 1.0f / (sqrtf(ss) + 1e-6f);
            #pragma unroll
            for (int ib = 0; ib < 4; ++ib) acc[ia][ib] *= sc;
        }
    }

    #pragma unroll
    for (int ia = 0; ia < 4; ++ia) {
        float4 v = make_float4(acc[ia][0], acc[ia][1], acc[ia][2], acc[ia][3]);
        *(float4*)&kvq[(size_t)(m0 + ty * 4 + ia) * PP + p0 + tx * 4] = v;
    }
}

// ---------------------------------------------------------------------------
// Sequential scan. One block per batch (16 blocks), 12 waves = 768 threads:
// wave (k,q) owns rows 16q..16q+15 of M[k]; lane (tr,tc) owns the 4x4 tile
// (16q+4tr, 4tc). Two lgkm-only barriers per step with role-specialized gate
// publication so consumers do ZERO sigmoids:
//   phase A: matvec partials; publish post-sigmoid row-gates (rg), delta, and
//            col-gate partials (cs) into LDS[pb].
//   barrier1
//   phase B: one wave per k sums 4 cs partials + bias + sigmoid -> cg_lds.
//   barrier2
//   phase C: everyone reads rg/cg/delta float4s, updates M, (k=0) output.
// Output Sq=M_new[0]@q_t is deferred one step into phase A (M == M_new(t-1)).
// ---------------------------------------------------------------------------
__global__ __launch_bounds__(768) void scan_kernel(
    const float* __restrict__ kvq,
    const float* __restrict__ M_init,
    const float* __restrict__ B_gates,
    float* __restrict__ d_out)
{
    const int b    = blockIdx.x;
    const int tid  = threadIdx.x;
    const int wid  = tid >> 6;        // 0..11
    const int k    = wid >> 2;        // 0..2 : which state matrix
    const int q    = wid & 3;         // row quarter
    const int lane = tid & 63;
    const int tr   = lane >> 4;       // 0..3
    const int tc   = lane & 15;       // 0..15
    const int kp   = (k + 2) % 3;     // gate target (k-1 mod 3)
    const int row0 = 16 * q + 4 * tr;
    const int col0 = 4 * tc;
    const int s3   = tc & 3;
    const int rowS = row0 + s3;       // row this lane finalizes

    __shared__ __align__(16) float rg_lds[2][3][64];      // post-sigmoid row gates
    __shared__ __align__(16) float cs_part[2][3][4][64];  // col-gate partials
    __shared__ __align__(16) float cg_lds[2][3][64];      // post-sigmoid col gates
    __shared__ __align__(16) float dl_lds[2][3][64];      // delta

    float M[4][4];
    #pragma unroll
    for (int i = 0; i < 4; ++i)
        load4(M[i], M_init + (((size_t)k * BB_ + b) * NN + row0 + i) * NN + col0);

    // Publisher biases: row-gate bias for kp's row rowS; col-gate bias (q==0).
    const float bias_pub_r = B_gates[kp * NN + rowS];
    const float bias_cg    = B_gates[k * NN + lane];

    float* outp = d_out;                           // [T][B][n]
    float* Mout = d_out + (size_t)TT * BB_ * NN;   // [K][B][n][n]

    // Per-lane offsets within a (t,b) row of kvq.
    const int o_knc = k * 128 + col0;
    const int o_wpc = kp * 128 + col0;
    const int o_wpr = kp * 128 + row0;
    const int o_v   = k * 128 + 64 + rowS;
    const int o_q   = 384 + col0;

    const float* kvt = kvq + (size_t)b * PP;
    float knc[4], wpc[4], wpr[4], qc[4], qp[4], vs;
    load4(knc, kvt + o_knc);
    load4(wpc, kvt + o_wpc);
    load4(wpr, kvt + o_wpr);
    vs = kvt[o_v];
    if (k == 0) load4(qc, kvt + o_q);
    #pragma unroll
    for (int j = 0; j < 4; ++j) qp[j] = (k == 0) ? qc[j] : 0.0f;

    #pragma unroll 2
    for (int t = 0; t < TT; ++t) {
        const int pb = t & 1;

        // Prefetch t+1 (stays in flight across both lgkm-only barriers).
        const float* kvn = (t + 1 < TT) ? (kvt + (size_t)BB_ * PP) : kvt;
        float nk[4], nwc[4], nwr[4], nq[4], nvs;
        load4(nk,  kvn + o_knc);
        load4(nwc, kvn + o_wpc);
        load4(nwr, kvn + o_wpr);
        nvs = kvn[o_v];
        if (k == 0) load4(nq, kvn + o_q);

        // ---- Phase A: matvec partials over the lane's 4x4 tile ----
        float rp[4] = {}, sp[4] = {}, cp[4] = {};
        #pragma unroll
        for (int i = 0; i < 4; ++i) {
            #pragma unroll
            for (int j = 0; j < 4; ++j) {
                const float m_ = M[i][j];
                rp[i] += m_ * knc[j];   // M[k]   @ kn[k]    (retrieve)
                sp[i] += m_ * wpc[j];   // M[k]   @ kn[kp]   (row gate of kp)
                cp[j] += m_ * wpr[i];   // M[k]^T @ kn[kp]   (col gate of kp)
            }
        }

        // Deferred output for t-1 (M == M_new(t-1)); k==0 only.
        if (k == 0) {
            float op[4] = {};
            #pragma unroll
            for (int i = 0; i < 4; ++i)
                #pragma unroll
                for (int j = 0; j < 4; ++j) op[i] += M[i][j] * qp[j];
            float ov = sel_reduce4(op, s3, 1);
            ov += __shfl_xor(ov, 4, 64);
            ov += __shfl_xor(ov, 8, 64);
            if (t > 0 && tc < 4)
                outp[((size_t)(t - 1) * BB_ + b) * NN + rowS] = ov * sigmoidf_(ov);
        }

        // Selective reduces (in-wave): one finalized row-component per lane.
        float rsv = sel_reduce4(sp, s3, 1);
        rsv += __shfl_xor(rsv, 4, 64);
        rsv += __shfl_xor(rsv, 8, 64);
        float rtv = sel_reduce4(rp, s3, 1);
        rtv += __shfl_xor(rtv, 4, 64);
        rtv += __shfl_xor(rtv, 8, 64);
        const float dv  = vs - rtv;                  // delta for row rowS
        const float csv = sel_reduce4(cp, tr, 16);   // col partial (this wave)

        if (tc < 4) {
            rg_lds[pb][kp][rowS] = sigmoidf_(rsv + bias_pub_r);  // final gate!
            dl_lds[pb][k][rowS]  = dv;
        }
        cs_part[pb][kp][q][col0 + tr] = csv;
        LDS_BARRIER();   // barrier 1

        // ---- Phase B: one wave per k finalizes that k's col gates ----
        if (q == 0) {
            const float s = cs_part[pb][k][0][lane] + cs_part[pb][k][1][lane]
                          + cs_part[pb][k][2][lane] + cs_part[pb][k][3][lane];
            cg_lds[pb][k][lane] = sigmoidf_(s + bias_cg);
        }
        LDS_BARRIER();   // barrier 2

        // ---- Phase C: consume final gates (no sigmoids), update M ----
        const float4 rg4 = *(const float4*)&rg_lds[pb][k][row0];
        const float4 cg4 = *(const float4*)&cg_lds[pb][k][col0];
        const float4 dl4 = *(const float4*)&dl_lds[pb][k][row0];
        const float rg[4] = {rg4.x, rg4.y, rg4.z, rg4.w};
        const float cg[4] = {cg4.x, cg4.y, cg4.z, cg4.w};
        const float dd[4] = {dl4.x, dl4.y, dl4.z, dl4.w};

        #pragma unroll
        for (int i = 0; i < 4; ++i) {
            #pragma unroll
            for (int j = 0; j < 4; ++j)
                M[i][j] = rg[i] * (M[i][j] * cg[j]) + dd[i] * knc[j];
        }

        // Rotate prefetch (unroll-2 lets the compiler rename these away).
        #pragma unroll
        for (int j = 0; j < 4; ++j) {
            qp[j] = qc[j];
            knc[j] = nk[j]; wpc[j] = nwc[j]; wpr[j] = nwr[j]; qc[j] = nq[j];
        }
        vs  = nvs;
        kvt = kvn;
    }

    // Flush deferred output for t = TT-1.
    if (k == 0) {
        float op[4] = {};
        #pragma unroll
        for (int i = 0; i < 4; ++i)
            #pragma unroll
            for (int j = 0; j < 4; ++j) op[i] += M[i][j] * qp[j];
        float ov = sel_reduce4(op, s3, 1);
        ov += __shfl_xor(ov, 4, 64);
        ov += __shfl_xor(ov, 8, 64);
        if (tc < 4)
            outp[((size_t)(TT - 1) * BB_ + b) * NN + rowS] = ov * sigmoidf_(ov);
    }

    // Final state write-out.
    #pragma unroll
    for (int i = 0; i < 4; ++i) {
        float4 v = make_float4(M[i][0], M[i][1], M[i][2], M[i][3]);
        *(float4*)&Mout[(((size_t)k * BB_ + b) * NN + row0 + i) * NN + col0] = v;
    }
}

extern "C" void kernel_launch(void* const* d_in, const int* in_sizes, int n_in,
                              void* d_out, int out_size, void* d_ws, size_t ws_size,
                              hipStream_t stream) {
    const float* x       = (const float*)d_in[0];
    const float* M_init  = (const float*)d_in[1];
    const float* W_kv    = (const float*)d_in[2];
    const float* W_q     = (const float*)d_in[3];
    const float* B_gates = (const float*)d_in[4];
    float* out = (float*)d_out;

    float* kvq = (float*)d_ws;   // [T*B][448] = 56 MB, k rows pre-normalized

    dim3 ggrid(TT * BB_ / 64, PP / 64);
    proj_gemm_kernel<<<ggrid, 256, 0, stream>>>(x, W_kv, W_q, kvq);

    scan_kernel<<<BB_, 768, 0, stream>>>(kvq, M_init, B_gates, out);
}

// Round 6
// 2676.295 us; speedup vs baseline: 3.5425x; 1.0773x over previous
//
#include <hip/hip_runtime.h>
#include <hip/hip_bf16.h>
#include <math.h>

// Problem constants (E83CircularTowerCell): T=2048, B=16, D=1024, n=64, K=3
#define TT 2048
#define BB_ 16
#define DD 1024
#define NN 64
#define KK 3
#define PP 448   // K*2*n + n = 384 + 64

typedef float  v2f  __attribute__((ext_vector_type(2)));
typedef float  f32x4 __attribute__((ext_vector_type(4)));
typedef short  bh8  __attribute__((ext_vector_type(8)));

__device__ __forceinline__ float sigmoidf_(float x) {
    return 1.0f / (1.0f + __expf(-x));
}

// LDS-ordering-only barrier: leaves global (vmcnt) loads in flight.
#define LDS_BARRIER() __asm__ volatile("s_waitcnt lgkmcnt(0)\n\ts_barrier" ::: "memory")

__device__ __forceinline__ void load4(float d[4], const float* p) {
    float4 t = *(const float4*)p;
    d[0] = t.x; d[1] = t.y; d[2] = t.z; d[3] = t.w;
}

// Selective butterfly: 4 partial components per lane, reduced across the
// 4-lane xor-group {mb, 2mb}; lane ends with full sum of component s.
__device__ __forceinline__ float sel_reduce4(const float v[4], int s, int mb) {
    const int s0 = s & 1, s1 = (s >> 1) & 1;
    float k0 = s0 ? v[1] : v[0], d0 = s0 ? v[0] : v[1];
    float k1 = s0 ? v[3] : v[2], d1 = s0 ? v[2] : v[3];
    float a0 = k0 + __shfl_xor(d0, mb, 64);
    float a1 = k1 + __shfl_xor(d1, mb, 64);
    float kb = s1 ? a1 : a0, db = s1 ? a0 : a1;
    return kb + __shfl_xor(db, 2 * mb, 64);
}

// ---------------------------------------------------------------------------
// W conversion: Wcat (448 x 1024 fp32, rows 0..383 = W_kv, 384..447 = W_q)
// -> Wsw[kb][n][kk] bf16, kb = k-chunk of 32 (kb = k>>5, kk = k&31).
// This layout makes every MFMA B-fragment (8 consecutive k for fixed n) a
// 16B-contiguous load with small per-tile strides.
// ---------------------------------------------------------------------------
__global__ __launch_bounds__(256) void cvt_w_kernel(
    const float* __restrict__ Wkv,
    const float* __restrict__ Wq,
    unsigned short* __restrict__ Wsw)
{
    const int n = blockIdx.x;
    const int tid = threadIdx.x;
    const float* row = (n < 384) ? (Wkv + (size_t)n * DD)
                                 : (Wq  + (size_t)(n - 384) * DD);
    const int idx = tid * 4;           // 4 consecutive k per thread
    const int kb = idx >> 5, kk = idx & 31;
    float4 f = *(const float4*)(row + idx);
    __hip_bfloat162 h0 = __float22bfloat162_rn(make_float2(f.x, f.y));
    __hip_bfloat162 h1 = __float22bfloat162_rn(make_float2(f.z, f.w));
    unsigned u0, u1;
    __builtin_memcpy(&u0, &h0, 4);
    __builtin_memcpy(&u1, &h1, 4);
    ushort4 o = make_ushort4((unsigned short)u0, (unsigned short)(u0 >> 16),
                             (unsigned short)u1, (unsigned short)(u1 >> 16));
    *(ushort4*)&Wsw[((size_t)kb * PP + n) * 32 + kk] = o;
}

// ---------------------------------------------------------------------------
// MFMA projection GEMM: kvq[m][p] = sum_d x[m,d] * Wcat[p][d], m = t*B+b.
// 64 rows/block, 256 threads; wave w owns rows m0+16w..+16, ALL 448 cols as
// 28 accumulators of 16x16 (x read once, converted to bf16 on the fly).
// K-loop: mfma_f32_16x16x32_bf16, A-frag = 8 contiguous x floats (cvt_pk),
// B-frag = 16B load from the swizzled bf16 W. Fused k-norm epilogue.
// ---------------------------------------------------------------------------
__global__ __launch_bounds__(256) void mfma_proj_kernel(
    const float* __restrict__ x,
    const unsigned short* __restrict__ Wsw,
    float* __restrict__ kvq)
{
    const int tid  = threadIdx.x;
    const int w    = tid >> 6;
    const int lane = tid & 63;
    const int ln   = lane & 15;
    const int quad = lane >> 4;
    const int m0   = blockIdx.x * 64;

    f32x4 acc[28];
    #pragma unroll
    for (int t = 0; t < 28; ++t) acc[t] = (f32x4){0.f, 0.f, 0.f, 0.f};

    const float* xrow = x + (size_t)(m0 + 16 * w + ln) * DD + quad * 8;

    for (int kb = 0; kb < 32; ++kb) {
        // A-fragment: 8 contiguous fp32 -> bf16x8 (A[m=ln][k=quad*8+j]).
        float4 a0 = *(const float4*)(xrow + kb * 32);
        float4 a1 = *(const float4*)(xrow + kb * 32 + 4);
        __hip_bfloat162 h0 = __float22bfloat162_rn(make_float2(a0.x, a0.y));
        __hip_bfloat162 h1 = __float22bfloat162_rn(make_float2(a0.z, a0.w));
        __hip_bfloat162 h2 = __float22bfloat162_rn(make_float2(a1.x, a1.y));
        __hip_bfloat162 h3 = __float22bfloat162_rn(make_float2(a1.z, a1.w));
        unsigned u0, u1, u2, u3;
        __builtin_memcpy(&u0, &h0, 4); __builtin_memcpy(&u1, &h1, 4);
        __builtin_memcpy(&u2, &h2, 4); __builtin_memcpy(&u3, &h3, 4);
        bh8 a;
        a[0] = (short)u0; a[1] = (short)(u0 >> 16);
        a[2] = (short)u1; a[3] = (short)(u1 >> 16);
        a[4] = (short)u2; a[5] = (short)(u2 >> 16);
        a[6] = (short)u3; a[7] = (short)(u3 >> 16);

        const unsigned short* wp_ = Wsw + (size_t)kb * PP * 32 + quad * 8;
        #pragma unroll
        for (int t = 0; t < 28; ++t) {
            const bh8 bfr = *(const bh8*)(wp_ + (16 * t + ln) * 32);
            acc[t] = __builtin_amdgcn_mfma_f32_16x16x32_bf16(a, bfr, acc[t], 0, 0, 0);
        }
    }

    // Fused k-norm: k-vectors live in col-tiles t=0..3 (k0), 8..11 (k1),
    // 16..19 (k2). D row = quad*4+reg; lanes of one quad share a row.
    #pragma unroll
    for (int g = 0; g < 3; ++g) {
        const int t0 = g * 8;
        #pragma unroll
        for (int reg = 0; reg < 4; ++reg) {
            float ss = acc[t0][reg] * acc[t0][reg]
                     + acc[t0 + 1][reg] * acc[t0 + 1][reg]
                     + acc[t0 + 2][reg] * acc[t0 + 2][reg]
                     + acc[t0 + 3][reg] * acc[t0 + 3][reg];
            #pragma unroll
            for (int m = 1; m <= 8; m <<= 1) ss += __shfl_xor(ss, m, 64);
            const float sc = 1.0f / (sqrtf(ss) + 1e-6f);
            #pragma unroll
            for (int t = t0; t < t0 + 4; ++t) acc[t][reg] *= sc;
        }
    }

    float* orow = kvq + (size_t)(m0 + 16 * w + quad * 4) * PP + ln;
    #pragma unroll
    for (int t = 0; t < 28; ++t)
        #pragma unroll
        for (int reg = 0; reg < 4; ++reg)
            orow[(size_t)reg * PP + 16 * t] = acc[t][reg];
}

// ---------------------------------------------------------------------------
// Sequential scan. One block per batch (16 blocks), 12 waves = 768 threads:
// wave (k,q) owns rows 16q..16q+15 of M[k]; lane (tr,tc) owns the 4x4 tile
// (16q+4tr, 4tc), stored as packed float2 pairs (v_pk_fma_f32 path).
// Two lgkm-only barriers/step, role-specialized gates (consumers: 0 sigmoids).
// ---------------------------------------------------------------------------
__global__ __launch_bounds__(768) void scan_kernel(
    const float* __restrict__ kvq,
    const float* __restrict__ M_init,
    const float* __restrict__ B_gates,
    float* __restrict__ d_out)
{
    const int b    = blockIdx.x;
    const int tid  = threadIdx.x;
    const int wid  = tid >> 6;        // 0..11
    const int k    = wid >> 2;        // 0..2 : which state matrix
    const int q    = wid & 3;         // row quarter
    const int lane = tid & 63;
    const int tr   = lane >> 4;       // 0..3
    const int tc   = lane & 15;       // 0..15
    const int kp   = (k + 2) % 3;     // gate target (k-1 mod 3)
    const int row0 = 16 * q + 4 * tr;
    const int col0 = 4 * tc;
    const int s3   = tc & 3;
    const int rowS = row0 + s3;       // row this lane finalizes

    __shared__ __align__(16) float rg_lds[2][3][64];      // post-sigmoid row gates
    __shared__ __align__(16) float cs_part[2][3][4][64];  // col-gate partials
    __shared__ __align__(16) float cg_lds[2][3][64];      // post-sigmoid col gates
    __shared__ __align__(16) float dl_lds[2][3][64];      // delta

    v2f M2[4][2];
    #pragma unroll
    for (int i = 0; i < 4; ++i) {
        float tmp[4];
        load4(tmp, M_init + (((size_t)k * BB_ + b) * NN + row0 + i) * NN + col0);
        M2[i][0] = (v2f){tmp[0], tmp[1]};
        M2[i][1] = (v2f){tmp[2], tmp[3]};
    }

    const float bias_pub_r = B_gates[kp * NN + rowS];
    const float bias_cg    = B_gates[k * NN + lane];

    float* outp = d_out;                           // [T][B][n]
    float* Mout = d_out + (size_t)TT * BB_ * NN;   // [K][B][n][n]

    const int o_knc = k * 128 + col0;
    const int o_wpc = kp * 128 + col0;
    const int o_wpr = kp * 128 + row0;
    const int o_v   = k * 128 + 64 + rowS;
    const int o_q   = 384 + col0;

    const float* kvt = kvq + (size_t)b * PP;
    v2f kn2[2], wc2[2], qc2[2], qp2[2];
    float wpr[4], vs;
    {
        float t4[4];
        load4(t4, kvt + o_knc); kn2[0] = (v2f){t4[0], t4[1]}; kn2[1] = (v2f){t4[2], t4[3]};
        load4(t4, kvt + o_wpc); wc2[0] = (v2f){t4[0], t4[1]}; wc2[1] = (v2f){t4[2], t4[3]};
        load4(wpr, kvt + o_wpr);
        vs = kvt[o_v];
        if (k == 0) {
            load4(t4, kvt + o_q);
            qc2[0] = (v2f){t4[0], t4[1]}; qc2[1] = (v2f){t4[2], t4[3]};
        } else { qc2[0] = (v2f){0.f, 0.f}; qc2[1] = qc2[0]; }
        qp2[0] = qc2[0]; qp2[1] = qc2[1];
    }

    #pragma unroll 2
    for (int t = 0; t < TT; ++t) {
        const int pb = t & 1;

        // Prefetch t+1 (stays in flight across both lgkm-only barriers).
        const float* kvn = (t + 1 < TT) ? (kvt + (size_t)BB_ * PP) : kvt;
        float nk[4], nwc[4], nwr[4], nq[4], nvs;
        load4(nk,  kvn + o_knc);
        load4(nwc, kvn + o_wpc);
        load4(nwr, kvn + o_wpr);
        nvs = kvn[o_v];
        if (k == 0) load4(nq, kvn + o_q);

        // ---- Phase A: packed matvec partials over the 4x4 tile ----
        v2f rp2[4], sp2[4], cp2[2];
        #pragma unroll
        for (int i = 0; i < 4; ++i) { rp2[i] = (v2f){0.f, 0.f}; sp2[i] = rp2[i]; }
        cp2[0] = (v2f){0.f, 0.f}; cp2[1] = cp2[0];
        #pragma unroll
        for (int i = 0; i < 4; ++i) {
            const v2f ws_ = (v2f){wpr[i], wpr[i]};
            rp2[i] += M2[i][0] * kn2[0] + M2[i][1] * kn2[1];
            sp2[i] += M2[i][0] * wc2[0] + M2[i][1] * wc2[1];
            cp2[0] += M2[i][0] * ws_;
            cp2[1] += M2[i][1] * ws_;
        }

        // Deferred output for t-1 (M == M_new(t-1)); k==0 only.
        if (k == 0) {
            float op[4];
            #pragma unroll
            for (int i = 0; i < 4; ++i) {
                v2f o2 = M2[i][0] * qp2[0] + M2[i][1] * qp2[1];
                op[i] = o2.x + o2.y;
            }
            float ov = sel_reduce4(op, s3, 1);
            ov += __shfl_xor(ov, 4, 64);
            ov += __shfl_xor(ov, 8, 64);
            if (t > 0 && tc < 4)
                outp[((size_t)(t - 1) * BB_ + b) * NN + rowS] = ov * sigmoidf_(ov);
        }

        // Horizontal halves -> scalar partial arrays.
        float rp[4], sp[4], cp[4];
        #pragma unroll
        for (int i = 0; i < 4; ++i) { rp[i] = rp2[i].x + rp2[i].y; sp[i] = sp2[i].x + sp2[i].y; }
        cp[0] = cp2[0].x; cp[1] = cp2[0].y; cp[2] = cp2[1].x; cp[3] = cp2[1].y;

        // Selective reduces (in-wave).
        float rsv = sel_reduce4(sp, s3, 1);
        rsv += __shfl_xor(rsv, 4, 64);
        rsv += __shfl_xor(rsv, 8, 64);
        float rtv = sel_reduce4(rp, s3, 1);
        rtv += __shfl_xor(rtv, 4, 64);
        rtv += __shfl_xor(rtv, 8, 64);
        const float dv  = vs - rtv;                  // delta for row rowS
        const float csv = sel_reduce4(cp, tr, 16);   // col partial (this wave)

        if (tc < 4) {
            rg_lds[pb][kp][rowS] = sigmoidf_(rsv + bias_pub_r);  // final gate
            dl_lds[pb][k][rowS]  = dv;
        }
        cs_part[pb][kp][q][col0 + tr] = csv;
        LDS_BARRIER();   // barrier 1

        // ---- Phase B: one wave per k finalizes that k's col gates ----
        if (q == 0) {
            const float s = cs_part[pb][k][0][lane] + cs_part[pb][k][1][lane]
                          + cs_part[pb][k][2][lane] + cs_part[pb][k][3][lane];
            cg_lds[pb][k][lane] = sigmoidf_(s + bias_cg);
        }
        LDS_BARRIER();   // barrier 2

        // ---- Phase C: consume final gates, packed update ----
        const float4 rg4 = *(const float4*)&rg_lds[pb][k][row0];
        const float4 cg4 = *(const float4*)&cg_lds[pb][k][col0];
        const float4 dl4 = *(const float4*)&dl_lds[pb][k][row0];
        const v2f cg2a = (v2f){cg4.x, cg4.y}, cg2b = (v2f){cg4.z, cg4.w};
        const float rg[4] = {rg4.x, rg4.y, rg4.z, rg4.w};
        const float dd[4] = {dl4.x, dl4.y, dl4.z, dl4.w};

        #pragma unroll
        for (int i = 0; i < 4; ++i) {
            const v2f r2 = (v2f){rg[i], rg[i]};
            const v2f d2 = (v2f){dd[i], dd[i]};
            M2[i][0] = r2 * (M2[i][0] * cg2a) + d2 * kn2[0];
            M2[i][1] = r2 * (M2[i][1] * cg2b) + d2 * kn2[1];
        }

        // Rotate prefetch.
        qp2[0] = qc2[0]; qp2[1] = qc2[1];
        kn2[0] = (v2f){nk[0], nk[1]};  kn2[1] = (v2f){nk[2], nk[3]};
        wc2[0] = (v2f){nwc[0], nwc[1]}; wc2[1] = (v2f){nwc[2], nwc[3]};
        #pragma unroll
        for (int j = 0; j < 4; ++j) wpr[j] = nwr[j];
        if (k == 0) { qc2[0] = (v2f){nq[0], nq[1]}; qc2[1] = (v2f){nq[2], nq[3]}; }
        vs  = nvs;
        kvt = kvn;
    }

    // Flush deferred output for t = TT-1.
    if (k == 0) {
        float op[4];
        #pragma unroll
        for (int i = 0; i < 4; ++i) {
            v2f o2 = M2[i][0] * qp2[0] + M2[i][1] * qp2[1];
            op[i] = o2.x + o2.y;
        }
        float ov = sel_reduce4(op, s3, 1);
        ov += __shfl_xor(ov, 4, 64);
        ov += __shfl_xor(ov, 8, 64);
        if (tc < 4)
            outp[((size_t)(TT - 1) * BB_ + b) * NN + rowS] = ov * sigmoidf_(ov);
    }

    // Final state write-out.
    #pragma unroll
    for (int i = 0; i < 4; ++i) {
        float4 v = make_float4(M2[i][0].x, M2[i][0].y, M2[i][1].x, M2[i][1].y);
        *(float4*)&Mout[(((size_t)k * BB_ + b) * NN + row0 + i) * NN + col0] = v;
    }
}

extern "C" void kernel_launch(void* const* d_in, const int* in_sizes, int n_in,
                              void* d_out, int out_size, void* d_ws, size_t ws_size,
                              hipStream_t stream) {
    const float* x       = (const float*)d_in[0];
    const float* M_init  = (const float*)d_in[1];
    const float* W_kv    = (const float*)d_in[2];
    const float* W_q     = (const float*)d_in[3];
    const float* B_gates = (const float*)d_in[4];
    float* out = (float*)d_out;

    float* kvq = (float*)d_ws;                       // 56 MB
    const size_t kvq_bytes = (size_t)TT * BB_ * PP * 4;
    unsigned short* Wsw = (unsigned short*)((char*)d_ws + kvq_bytes);  // 896 KB

    cvt_w_kernel<<<PP, 256, 0, stream>>>(W_kv, W_q, Wsw);
    mfma_proj_kernel<<<TT * BB_ / 64, 256, 0, stream>>>(x, Wsw, kvq);
    scan_kernel<<<BB_, 768, 0, stream>>>(kvq, M_init, B_gates, out);
}